// Round 5
// baseline (773.826 us; speedup 1.0000x reference)
//
#include <hip/hip_runtime.h>
#include <hip/hip_bf16.h>
#include <hip/hip_fp16.h>

// Problem constants
#define BS    8192
#define DIM   256
#define MROWS 128
#define NCOLS 128
#define KTOT  (MROWS * NCOLS)   // 16384 codebook entries
#define CAND_CAP 131072
#define MARGIN 1.0f

typedef __attribute__((ext_vector_type(8))) short short8;
typedef __attribute__((ext_vector_type(8))) _Float16 half8;
typedef __attribute__((ext_vector_type(4))) float f32x4;
typedef unsigned long long u64;

// f32 -> bf16 round-to-nearest-even (bit trick; inputs finite)
__device__ inline ushort f2bf(float f) {
    unsigned int x = __float_as_uint(f);
    return (ushort)((x + 0x7FFFu + ((x >> 16) & 1u)) >> 16);
}

// async global->LDS, 16B per lane; lds dest = wave-uniform base + lane*16
__device__ inline void gload_lds16(const void* g, void* l) {
    __builtin_amdgcn_global_load_lds(
        (const __attribute__((address_space(1))) unsigned int*)g,
        (__attribute__((address_space(3))) unsigned int*)l, 16, 0, 0);
}

// order-preserving f32 -> u32 map (ascending) and inverse
__device__ inline unsigned int fmap(float f) {
    unsigned int b = __float_as_uint(f);
    return (b & 0x80000000u) ? ~b : (b | 0x80000000u);
}
__device__ inline float unfmap(unsigned int m) {
    return (m & 0x80000000u) ? __uint_as_float(m & 0x7FFFFFFFu)
                             : __uint_as_float(~m);
}

// ---------------------------------------------------------------------------
// x -> fp16 (for BMU approx passes)
__global__ void cvt_x_f16_kernel(const float* __restrict__ x, ushort* __restrict__ xf) {
    int idx = blockIdx.x * 256 + threadIdx.x;
    float4 v = *(const float4*)&x[(size_t)idx * 4];
    ushort4 h;
    h.x = __half_as_ushort(__float2half(v.x));
    h.y = __half_as_ushort(__float2half(v.y));
    h.z = __half_as_ushort(__float2half(v.z));
    h.w = __half_as_ushort(__float2half(v.w));
    *(ushort4*)&xf[(size_t)idx * 4] = h;
}

// w -> fp16 + wsq, one wave per row (4 rows/block).
__global__ void cvt_w_f16_kernel(const float* __restrict__ w, ushort* __restrict__ wf,
                                 float* __restrict__ wsq) {
    int wid = threadIdx.x >> 6, lane = threadIdx.x & 63;
    size_t row = blockIdx.x * 4 + wid;
    float4 v = *(const float4*)&w[row * DIM + lane * 4];
    ushort4 h;
    h.x = __half_as_ushort(__float2half(v.x));
    h.y = __half_as_ushort(__float2half(v.y));
    h.z = __half_as_ushort(__float2half(v.z));
    h.w = __half_as_ushort(__float2half(v.w));
    *(ushort4*)&wf[row * DIM + lane * 4] = h;
    float s = v.x * v.x + v.y * v.y + v.z * v.z + v.w * v.w;
    #pragma unroll
    for (int off = 32; off; off >>= 1) s += __shfl_down(s, off, 64);
    if (lane == 0) wsq[row] = s;
}

// ---------------------------------------------------------------------------
__global__ void init_keys_kernel(u64* __restrict__ keys) {
    int i = blockIdx.x * 256 + threadIdx.x;
    keys[i] = ~0ULL;
}

__global__ void zero_out_kernel(float* __restrict__ p) {
    int idx = blockIdx.x * 256 + threadIdx.x;
    *(float4*)&p[idx * 4] = make_float4(0.f, 0.f, 0.f, 0.f);
}

__global__ void zero_small_kernel(float* __restrict__ denom, unsigned int* __restrict__ cnt) {
    int idx = blockIdx.x * 256 + threadIdx.x;
    denom[idx] = 0.f;
    if (idx == 0) cnt[0] = 0u;
}

// ---------------------------------------------------------------------------
// BMU pass 1: fp16 1-pass GEMM, tile 128 samples x 256 k, K=256, BK=32.
// Approx score = wsq[k] - 2*dot_fp16; per-sample packed-u64 atomicMin.
__global__ __launch_bounds__(256) void bmu_pass1_kernel(
    const ushort* __restrict__ xf, const ushort* __restrict__ wf,
    const float* __restrict__ wsq, u64* __restrict__ keys) {
    __shared__ ushort A[128 * 32];   //  8 KB
    __shared__ ushort B[256 * 32];   // 16 KB
    __shared__ u64 red[128][2];      //  2 KB

    int m0 = blockIdx.x * 128;
    int k0 = blockIdx.y * 256;
    int tid = threadIdx.x, w = tid >> 6, lane = tid & 63;
    int wm = (w & 1) * 64, wn = (w >> 1) * 128;
    int lm = lane & 15, quad = lane >> 4;
    int srow = lane >> 2, scol = (lane & 3) * 8;

    f32x4 acc[4][8];
    #pragma unroll
    for (int mi = 0; mi < 4; ++mi)
        #pragma unroll
        for (int ni = 0; ni < 8; ++ni)
            acc[mi][ni] = (f32x4){0.f, 0.f, 0.f, 0.f};

    for (int kb = 0; kb < DIM; kb += 32) {
        size_t axoff = (size_t)(m0 + w * 32 + srow) * DIM + kb + scol;
        size_t bxoff = (size_t)(k0 + w * 64 + srow) * DIM + kb + scol;
        gload_lds16(xf + axoff,            &A[(w * 32) * 32]);
        gload_lds16(xf + axoff + 16 * DIM, &A[(w * 32 + 16) * 32]);
        gload_lds16(wf + bxoff,            &B[(w * 64) * 32]);
        gload_lds16(wf + bxoff + 16 * DIM, &B[(w * 64 + 16) * 32]);
        gload_lds16(wf + bxoff + 32 * DIM, &B[(w * 64 + 32) * 32]);
        gload_lds16(wf + bxoff + 48 * DIM, &B[(w * 64 + 48) * 32]);
        __syncthreads();
        half8 av[4], bv[8];
        #pragma unroll
        for (int mi = 0; mi < 4; ++mi)
            av[mi] = *(const half8*)&A[(wm + mi * 16 + lm) * 32 + quad * 8];
        #pragma unroll
        for (int ni = 0; ni < 8; ++ni)
            bv[ni] = *(const half8*)&B[(wn + ni * 16 + lm) * 32 + quad * 8];
        #pragma unroll
        for (int mi = 0; mi < 4; ++mi)
            #pragma unroll
            for (int ni = 0; ni < 8; ++ni)
                acc[mi][ni] = __builtin_amdgcn_mfma_f32_16x16x32_f16(
                    av[mi], bv[ni], acc[mi][ni], 0, 0, 0);
        __syncthreads();
    }

    float wsqv[8];
    #pragma unroll
    for (int ni = 0; ni < 8; ++ni) wsqv[ni] = wsq[k0 + wn + ni * 16 + lm];

    #pragma unroll
    for (int mi = 0; mi < 4; ++mi) {
        #pragma unroll
        for (int r = 0; r < 4; ++r) {
            u64 best = ~0ULL;
            #pragma unroll
            for (int ni = 0; ni < 8; ++ni) {
                float sc = fmaf(-2.0f, acc[mi][ni][r], wsqv[ni]);
                u64 p = ((u64)fmap(sc) << 32) |
                        (unsigned int)(k0 + wn + ni * 16 + lm);
                best = p < best ? p : best;
            }
            #pragma unroll
            for (int mask = 1; mask < 16; mask <<= 1) {
                u64 o = __shfl_xor(best, mask, 64);
                best = o < best ? o : best;
            }
            if (lm == 0) red[wm + mi * 16 + quad * 4 + r][w >> 1] = best;
        }
    }
    __syncthreads();
    if (tid < 128) {
        u64 a = red[tid][0], b = red[tid][1];
        atomicMin(&keys[m0 + tid], a < b ? a : b);
    }
}

// ---------------------------------------------------------------------------
// BMU pass 2: identical GEMM (bit-identical scores); select all k with
// score <= approxmin + MARGIN (hard-covers fp16 worst-case error) -> cand list.
__global__ __launch_bounds__(256) void bmu_pass2_kernel(
    const ushort* __restrict__ xf, const ushort* __restrict__ wf,
    const float* __restrict__ wsq, const u64* __restrict__ keys,
    u64* __restrict__ cand, unsigned int* __restrict__ cnt) {
    __shared__ ushort A[128 * 32];
    __shared__ ushort B[256 * 32];

    int m0 = blockIdx.x * 128;
    int k0 = blockIdx.y * 256;
    int tid = threadIdx.x, w = tid >> 6, lane = tid & 63;
    int wm = (w & 1) * 64, wn = (w >> 1) * 128;
    int lm = lane & 15, quad = lane >> 4;
    int srow = lane >> 2, scol = (lane & 3) * 8;

    f32x4 acc[4][8];
    #pragma unroll
    for (int mi = 0; mi < 4; ++mi)
        #pragma unroll
        for (int ni = 0; ni < 8; ++ni)
            acc[mi][ni] = (f32x4){0.f, 0.f, 0.f, 0.f};

    for (int kb = 0; kb < DIM; kb += 32) {
        size_t axoff = (size_t)(m0 + w * 32 + srow) * DIM + kb + scol;
        size_t bxoff = (size_t)(k0 + w * 64 + srow) * DIM + kb + scol;
        gload_lds16(xf + axoff,            &A[(w * 32) * 32]);
        gload_lds16(xf + axoff + 16 * DIM, &A[(w * 32 + 16) * 32]);
        gload_lds16(wf + bxoff,            &B[(w * 64) * 32]);
        gload_lds16(wf + bxoff + 16 * DIM, &B[(w * 64 + 16) * 32]);
        gload_lds16(wf + bxoff + 32 * DIM, &B[(w * 64 + 32) * 32]);
        gload_lds16(wf + bxoff + 48 * DIM, &B[(w * 64 + 48) * 32]);
        __syncthreads();
        half8 av[4], bv[8];
        #pragma unroll
        for (int mi = 0; mi < 4; ++mi)
            av[mi] = *(const half8*)&A[(wm + mi * 16 + lm) * 32 + quad * 8];
        #pragma unroll
        for (int ni = 0; ni < 8; ++ni)
            bv[ni] = *(const half8*)&B[(wn + ni * 16 + lm) * 32 + quad * 8];
        #pragma unroll
        for (int mi = 0; mi < 4; ++mi)
            #pragma unroll
            for (int ni = 0; ni < 8; ++ni)
                acc[mi][ni] = __builtin_amdgcn_mfma_f32_16x16x32_f16(
                    av[mi], bv[ni], acc[mi][ni], 0, 0, 0);
        __syncthreads();
    }

    float wsqv[8];
    #pragma unroll
    for (int ni = 0; ni < 8; ++ni) wsqv[ni] = wsq[k0 + wn + ni * 16 + lm];

    #pragma unroll
    for (int mi = 0; mi < 4; ++mi) {
        #pragma unroll
        for (int r = 0; r < 4; ++r) {
            int s = m0 + wm + mi * 16 + quad * 4 + r;
            float thr = unfmap((unsigned int)(keys[s] >> 32)) + MARGIN;
            #pragma unroll
            for (int ni = 0; ni < 8; ++ni) {
                float sc = fmaf(-2.0f, acc[mi][ni][r], wsqv[ni]);
                if (sc <= thr) {
                    unsigned int idx = atomicAdd(cnt, 1u);
                    if (idx < CAND_CAP)
                        cand[idx] = ((u64)(unsigned int)s << 32) |
                                    (unsigned int)(k0 + wn + ni * 16 + lm);
                }
            }
        }
    }
}

// ---------------------------------------------------------------------------
// BMU refine: exact f32 dist^2 per candidate, one wave per candidate (strided).
__global__ __launch_bounds__(256) void bmu_refine_kernel(
    const float* __restrict__ x, const float* __restrict__ w,
    const u64* __restrict__ cand, const unsigned int* __restrict__ cnt,
    u64* __restrict__ keys2) {
    int lane = threadIdx.x & 63;
    int wid = blockIdx.x * 4 + (threadIdx.x >> 6);
    unsigned int n = cnt[0];
    if (n > CAND_CAP) n = CAND_CAP;
    for (unsigned int c = wid; c < n; c += 128 * 4) {
        u64 e = cand[c];
        unsigned int s = (unsigned int)(e >> 32);
        unsigned int k = (unsigned int)e;
        float4 xv = *(const float4*)&x[(size_t)s * DIM + lane * 4];
        float4 wv = *(const float4*)&w[(size_t)k * DIM + lane * 4];
        float dx = xv.x - wv.x, dy = xv.y - wv.y;
        float dz = xv.z - wv.z, dw = xv.w - wv.w;
        float d = dx * dx + dy * dy + dz * dz + dw * dw;
        #pragma unroll
        for (int off = 32; off; off >>= 1) d += __shfl_down(d, off, 64);
        if (lane == 0)
            atomicMin(&keys2[s], ((u64)fmap(d) << 32) | k);
    }
}

// ---------------------------------------------------------------------------
// px/py Gaussian tables (lr cancels in numer/denom; dropped).
__global__ void pxy_kernel(const u64* __restrict__ keys,
                           const int* __restrict__ it_p,
                           float* __restrict__ px, float* __restrict__ py) {
    int b = blockIdx.x;
    int tid = threadIdx.x;
    unsigned int k = (unsigned int)(keys[b] & 0xFFFFFFFFu);
    int w0 = (int)(k >> 7), w1 = (int)(k & 127);
    float itf = (float)it_p[0];
    const float START_SIGMA = 64.0f;
    const float TAU = (float)(20.0 / 4.1588830833596715);  // 20 / ln(64)
    float sigma = START_SIGMA * expf(-itf / TAU);
    float d2 = 2.0f * sigma * sigma;
    if (tid < 128) {
        float diff = (float)(tid - w0);
        px[b * 128 + tid] = expf(-(diff * diff) / d2);
    } else {
        int j = tid - 128;
        float diff = (float)(j - w1);
        py[b * 128 + j] = expf(-(diff * diff) / d2);
    }
}

// ---------------------------------------------------------------------------
// Transpose f32 [rows][cols] -> [cols][rows], 64x64 tiles.
__global__ void tpose_f32_kernel(const float* __restrict__ in, float* __restrict__ outT,
                                 int rows, int cols) {
    __shared__ float tile[64][68];
    int b0 = blockIdx.x * 64;
    int c0 = blockIdx.y * 64;
    int t = threadIdx.x;
    int rr = t >> 4, seg = t & 15;
    #pragma unroll
    for (int p = 0; p < 4; ++p) {
        int row = rr + p * 16;
        float4 v = *(const float4*)&in[(size_t)(b0 + row) * cols + c0 + seg * 4];
        tile[seg * 4 + 0][row] = v.x; tile[seg * 4 + 1][row] = v.y;
        tile[seg * 4 + 2][row] = v.z; tile[seg * 4 + 3][row] = v.w;
    }
    __syncthreads();
    #pragma unroll
    for (int p = 0; p < 4; ++p) {
        int crow = rr + p * 16;
        *(float4*)&outT[(size_t)(c0 + crow) * rows + b0 + seg * 4] =
            *(float4*)&tile[crow][seg * 4];
    }
}

// Transpose + f32->bf16: data [8192][256] -> xT [256][8192] (ushort).
__global__ void tpose_cvt_bf16_kernel(const float* __restrict__ in, ushort* __restrict__ outT) {
    __shared__ float tile[64][68];
    int b0 = blockIdx.x * 64;
    int d0 = blockIdx.y * 64;
    int t = threadIdx.x;
    int rr = t >> 4, seg = t & 15;
    #pragma unroll
    for (int p = 0; p < 4; ++p) {
        int row = rr + p * 16;
        float4 v = *(const float4*)&in[(size_t)(b0 + row) * DIM + d0 + seg * 4];
        tile[seg * 4 + 0][row] = v.x; tile[seg * 4 + 1][row] = v.y;
        tile[seg * 4 + 2][row] = v.z; tile[seg * 4 + 3][row] = v.w;
    }
    __syncthreads();
    #pragma unroll
    for (int p = 0; p < 4; ++p) {
        int drow = rr + p * 16;
        float4 v = *(float4*)&tile[drow][seg * 4];
        ushort4 u;
        u.x = f2bf(v.x); u.y = f2bf(v.y); u.z = f2bf(v.z); u.w = f2bf(v.w);
        *(ushort4*)&outT[(size_t)(d0 + drow) * BS + b0 + seg * 4] = u;
    }
}

// ---------------------------------------------------------------------------
// denom[i][j] = sum_b px[b][i]*py[b][j] as block-parallel outer product.
__global__ __launch_bounds__(256) void denom_op_kernel(
    const float* __restrict__ px, const float* __restrict__ py,
    float* __restrict__ denom) {
    __shared__ float pxs[64][128];   // 32 KB
    __shared__ float pys[64][128];   // 32 KB
    int b0 = blockIdx.x * 64;
    int tid = threadIdx.x;
    #pragma unroll
    for (int q = 0; q < 8; ++q) {
        int idx = q * 256 + tid;
        int row = idx >> 5;
        int col = (idx & 31) * 4;
        *(float4*)&pxs[row][col] = *(const float4*)&px[(size_t)(b0 + row) * 128 + col];
        *(float4*)&pys[row][col] = *(const float4*)&py[(size_t)(b0 + row) * 128 + col];
    }
    __syncthreads();
    int ig = tid >> 4, jg = tid & 15;
    float acc[8][8] = {};
    for (int b = 0; b < 64; ++b) {
        float pv[8], qv[8];
        *(float4*)&pv[0] = *(float4*)&pxs[b][ig * 8];
        *(float4*)&pv[4] = *(float4*)&pxs[b][ig * 8 + 4];
        *(float4*)&qv[0] = *(float4*)&pys[b][jg * 8];
        *(float4*)&qv[4] = *(float4*)&pys[b][jg * 8 + 4];
        #pragma unroll
        for (int ii = 0; ii < 8; ++ii)
            #pragma unroll
            for (int jj = 0; jj < 8; ++jj)
                acc[ii][jj] = fmaf(pv[ii], qv[jj], acc[ii][jj]);
    }
    #pragma unroll
    for (int ii = 0; ii < 8; ++ii)
        #pragma unroll
        for (int jj = 0; jj < 8; ++jj)
            atomicAdd(&denom[(ig * 8 + ii) * 128 + jg * 8 + jj], acc[ii][jj]);
}

// ---------------------------------------------------------------------------
// numer = P^T X via bf16 MFMA.  Tile M=128 (j), N=256 (all d), K=2048.
// Grid (128 i x 4 ksplits) = 512 blocks; A computed at staging, B via
// global_load_lds; atomicAdd partials into zeroed out.
__global__ __launch_bounds__(256) void numer_mfma_kernel(
    const float* __restrict__ pxT, const float* __restrict__ pyT,
    const ushort* __restrict__ xT, float* __restrict__ out) {
    __shared__ ushort Alds[128 * 32];   //  8 KB
    __shared__ ushort Blds[256 * 32];   // 16 KB

    int i   = blockIdx.x;
    int ks  = blockIdx.y;
    int tid = threadIdx.x;
    int w = tid >> 6, lane = tid & 63;
    int wm = (w & 1) * 64, wn = (w >> 1) * 128;
    int lm = lane & 15, quad = lane >> 4;

    f32x4 acc[4][8];
    #pragma unroll
    for (int mi = 0; mi < 4; ++mi)
        #pragma unroll
        for (int ni = 0; ni < 8; ++ni)
            acc[mi][ni] = (f32x4){0.f, 0.f, 0.f, 0.f};

    const float* pxrow = pxT + (size_t)i * BS;
    int aj0 = tid >> 2;
    int ab  = (tid & 3) * 8;
    int brl = w * 64 + (lane >> 2);
    int bcl = (lane & 3) * 8;

    for (int kb = ks * 2048; kb < ks * 2048 + 2048; kb += 32) {
        gload_lds16(xT + (size_t)(brl) * BS + kb + bcl,       &Blds[(w * 64) * 32]);
        gload_lds16(xT + (size_t)(brl + 16) * BS + kb + bcl,  &Blds[(w * 64 + 16) * 32]);
        gload_lds16(xT + (size_t)(brl + 32) * BS + kb + bcl,  &Blds[(w * 64 + 32) * 32]);
        gload_lds16(xT + (size_t)(brl + 48) * BS + kb + bcl,  &Blds[(w * 64 + 48) * 32]);
        #pragma unroll
        for (int ph = 0; ph < 2; ++ph) {
            int j = aj0 + ph * 64;
            const float* pyr = pyT + (size_t)j * BS + kb + ab;
            float4 y0 = *(const float4*)pyr;
            float4 y1 = *(const float4*)(pyr + 4);
            float4 x0 = *(const float4*)&pxrow[kb + ab];
            float4 x1 = *(const float4*)&pxrow[kb + ab + 4];
            union { ushort u[8]; float4 v; } pk;
            pk.u[0] = f2bf(y0.x * x0.x); pk.u[1] = f2bf(y0.y * x0.y);
            pk.u[2] = f2bf(y0.z * x0.z); pk.u[3] = f2bf(y0.w * x0.w);
            pk.u[4] = f2bf(y1.x * x1.x); pk.u[5] = f2bf(y1.y * x1.y);
            pk.u[6] = f2bf(y1.z * x1.z); pk.u[7] = f2bf(y1.w * x1.w);
            *(float4*)&Alds[j * 32 + ab] = pk.v;
        }
        __syncthreads();
        short8 af[4], bg[8];
        #pragma unroll
        for (int mi = 0; mi < 4; ++mi)
            af[mi] = *(const short8*)&Alds[(wm + mi * 16 + lm) * 32 + quad * 8];
        #pragma unroll
        for (int ni = 0; ni < 8; ++ni)
            bg[ni] = *(const short8*)&Blds[(wn + ni * 16 + lm) * 32 + quad * 8];
        #pragma unroll
        for (int mi = 0; mi < 4; ++mi)
            #pragma unroll
            for (int ni = 0; ni < 8; ++ni)
                acc[mi][ni] = __builtin_amdgcn_mfma_f32_16x16x32_bf16(
                    af[mi], bg[ni], acc[mi][ni], 0, 0, 0);
        __syncthreads();
    }
    #pragma unroll
    for (int mi = 0; mi < 4; ++mi) {
        int j = i * 128 + wm + mi * 16 + quad * 4;
        #pragma unroll
        for (int ni = 0; ni < 8; ++ni) {
            int d = wn + ni * 16 + lm;
            float* op = &out[(size_t)j * DIM + d];
            atomicAdd(op + 0 * DIM, acc[mi][ni][0]);
            atomicAdd(op + 1 * DIM, acc[mi][ni][1]);
            atomicAdd(op + 2 * DIM, acc[mi][ni][2]);
            atomicAdd(op + 3 * DIM, acc[mi][ni][3]);
        }
    }
}

// ---------------------------------------------------------------------------
// finalize: out = denom!=0 ? out/denom : w
__global__ void finalize_kernel(float* __restrict__ out, const float* __restrict__ denom,
                                const float* __restrict__ w) {
    int idx = blockIdx.x * 256 + threadIdx.x;
    int e = idx * 4;
    int k = e >> 8;
    float dv = denom[k];
    float4 nv = *(float4*)&out[e];
    float4 wv = *(const float4*)&w[e];
    float4 r;
    if (dv != 0.0f) {
        r.x = nv.x / dv; r.y = nv.y / dv; r.z = nv.z / dv; r.w = nv.w / dv;
    } else {
        r = wv;
    }
    *(float4*)&out[e] = r;
}

// ---------------------------------------------------------------------------
extern "C" void kernel_launch(void* const* d_in, const int* in_sizes, int n_in,
                              void* d_out, int out_size, void* d_ws, size_t ws_size,
                              hipStream_t stream) {
    const float* data = (const float*)d_in[0];   // [8192, 256] f32
    const float* w    = (const float*)d_in[1];   // [128,128,256] f32
    const int*   itp  = (const int*)d_in[2];     // scalar
    float* out = (float*)d_out;                  // [128,128,256] f32

    char* ws = (char*)d_ws;
    size_t off = 0;
    float*        wsq   = (float*)(ws + off);        off += 65536;     //  64 KB
    u64*          keys  = (u64*)(ws + off);          off += 65536;     //  64 KB (approx)
    u64*          keys2 = (u64*)(ws + off);          off += 65536;     //  64 KB (exact)
    unsigned int* cnt   = (unsigned int*)(ws + off); off += 65536;     //  64 KB
    float*        px    = (float*)(ws + off);        off += 4194304;   //   4 MB [b][i]
    float*        py    = (float*)(ws + off);        off += 4194304;   //   4 MB [b][j]
    float*        denom = (float*)(ws + off);        off += 65536;     //  64 KB
    float*        pxT   = (float*)(ws + off);        off += 4194304;   //   4 MB [i][b]
    float*        pyT   = (float*)(ws + off);        off += 4194304;   //   4 MB [j][b]
    ushort*       xT    = (ushort*)(ws + off);       off += 4194304;   //   4 MB [d][b] bf16
    ushort*       xf    = (ushort*)(ws + off);       off += 4194304;   //   4 MB [b][d] fp16
    ushort*       wf    = (ushort*)(ws + off);       off += 8388608;   //   8 MB [k][d] fp16
    u64*          cand  = (u64*)(ws + off);          off += 1048576;   //   1 MB

    zero_out_kernel<<<KTOT * DIM / 1024, 256, 0, stream>>>(out);
    zero_small_kernel<<<KTOT / 256, 256, 0, stream>>>(denom, cnt);
    init_keys_kernel<<<BS / 256, 256, 0, stream>>>(keys);
    init_keys_kernel<<<BS / 256, 256, 0, stream>>>(keys2);
    cvt_x_f16_kernel<<<BS * DIM / 1024, 256, 0, stream>>>(data, xf);
    cvt_w_f16_kernel<<<KTOT / 4, 256, 0, stream>>>(w, wf, wsq);
    tpose_cvt_bf16_kernel<<<dim3(BS / 64, DIM / 64), 256, 0, stream>>>(data, xT);
    bmu_pass1_kernel<<<dim3(64, 64), 256, 0, stream>>>(xf, wf, wsq, keys);
    bmu_pass2_kernel<<<dim3(64, 64), 256, 0, stream>>>(xf, wf, wsq, keys, cand, cnt);
    bmu_refine_kernel<<<128, 256, 0, stream>>>(data, w, cand, cnt, keys2);
    pxy_kernel<<<BS, 256, 0, stream>>>(keys2, itp, px, py);
    tpose_f32_kernel<<<dim3(BS / 64, 2), 256, 0, stream>>>(px, pxT, BS, 128);
    tpose_f32_kernel<<<dim3(BS / 64, 2), 256, 0, stream>>>(py, pyT, BS, 128);
    denom_op_kernel<<<128, 256, 0, stream>>>(px, py, denom);
    numer_mfma_kernel<<<dim3(128, 4), 256, 0, stream>>>(pxT, pyT, xT, out);
    finalize_kernel<<<KTOT * DIM / 1024, 256, 0, stream>>>(out, denom, w);
}

// Round 6
// 624.274 us; speedup vs baseline: 1.2396x; 1.2396x over previous
//
#include <hip/hip_runtime.h>
#include <hip/hip_bf16.h>
#include <hip/hip_fp16.h>

// Problem constants
#define BS    8192
#define DIM   256
#define MROWS 128
#define NCOLS 128
#define KTOT  (MROWS * NCOLS)   // 16384 codebook entries
#define CAND_CAP 131072
#define MARGIN 1.0f

typedef __attribute__((ext_vector_type(8))) _Float16 half8;
typedef __attribute__((ext_vector_type(4))) float f32x4;
typedef unsigned long long u64;

__device__ inline ushort f2h(float f) { return __half_as_ushort(__float2half(f)); }

// async global->LDS, 16B per lane; lds dest = wave-uniform base + lane*16
__device__ inline void gload_lds16(const void* g, void* l) {
    __builtin_amdgcn_global_load_lds(
        (const __attribute__((address_space(1))) unsigned int*)g,
        (__attribute__((address_space(3))) unsigned int*)l, 16, 0, 0);
}

// order-preserving f32 -> u32 map (ascending) and inverse
__device__ inline unsigned int fmap(float f) {
    unsigned int b = __float_as_uint(f);
    return (b & 0x80000000u) ? ~b : (b | 0x80000000u);
}
__device__ inline float unfmap(unsigned int m) {
    return (m & 0x80000000u) ? __uint_as_float(m & 0x7FFFFFFFu)
                             : __uint_as_float(~m);
}

// ---------------------------------------------------------------------------
// data -> fp16 row-major (xf) AND fp16 transposed (xfT) in one pass.
__global__ void cvt_x_kernel(const float* __restrict__ in, ushort* __restrict__ xf,
                             ushort* __restrict__ xfT) {
    __shared__ float tile[64][68];
    int b0 = blockIdx.x * 64;
    int d0 = blockIdx.y * 64;
    int t = threadIdx.x;
    int rr = t >> 4, seg = t & 15;
    #pragma unroll
    for (int p = 0; p < 4; ++p) {
        int row = rr + p * 16;
        float4 v = *(const float4*)&in[(size_t)(b0 + row) * DIM + d0 + seg * 4];
        ushort4 h;
        h.x = f2h(v.x); h.y = f2h(v.y); h.z = f2h(v.z); h.w = f2h(v.w);
        *(ushort4*)&xf[(size_t)(b0 + row) * DIM + d0 + seg * 4] = h;
        tile[seg * 4 + 0][row] = v.x; tile[seg * 4 + 1][row] = v.y;
        tile[seg * 4 + 2][row] = v.z; tile[seg * 4 + 3][row] = v.w;
    }
    __syncthreads();
    #pragma unroll
    for (int p = 0; p < 4; ++p) {
        int drow = rr + p * 16;
        float4 v = *(float4*)&tile[drow][seg * 4];
        ushort4 h;
        h.x = f2h(v.x); h.y = f2h(v.y); h.z = f2h(v.z); h.w = f2h(v.w);
        *(ushort4*)&xfT[(size_t)(d0 + drow) * BS + b0 + seg * 4] = h;
    }
}

// w -> fp16 + wsq, one wave per row (4 rows/block).
__global__ void cvt_w_f16_kernel(const float* __restrict__ w, ushort* __restrict__ wf,
                                 float* __restrict__ wsq) {
    int wid = threadIdx.x >> 6, lane = threadIdx.x & 63;
    size_t row = blockIdx.x * 4 + wid;
    float4 v = *(const float4*)&w[row * DIM + lane * 4];
    ushort4 h;
    h.x = f2h(v.x); h.y = f2h(v.y); h.z = f2h(v.z); h.w = f2h(v.w);
    *(ushort4*)&wf[row * DIM + lane * 4] = h;
    float s = v.x * v.x + v.y * v.y + v.z * v.z + v.w * v.w;
    #pragma unroll
    for (int off = 32; off; off >>= 1) s += __shfl_down(s, off, 64);
    if (lane == 0) wsq[row] = s;
}

// ---------------------------------------------------------------------------
// setup: zero denom, init keys/keys2 to +inf, zero cnt.  Grid KTOT/256.
__global__ void setup_kernel(float* __restrict__ denom, u64* __restrict__ keys,
                             u64* __restrict__ keys2, unsigned int* __restrict__ cnt) {
    int idx = blockIdx.x * 256 + threadIdx.x;
    denom[idx] = 0.f;
    if (idx < BS) { keys[idx] = ~0ULL; keys2[idx] = ~0ULL; }
    if (idx == 0) cnt[0] = 0u;
}

__global__ void zero_out_kernel(float* __restrict__ p) {
    int idx = blockIdx.x * 256 + threadIdx.x;
    *(float4*)&p[idx * 4] = make_float4(0.f, 0.f, 0.f, 0.f);
}

// ---------------------------------------------------------------------------
// BMU pass 1: fp16 GEMM, tile 128 samples x 128 k (acc[4][4] => 3 waves/SIMD).
// Approx score = wsq[k] - 2*dot_fp16; per-sample packed-u64 atomicMin.
__global__ __launch_bounds__(256) void bmu_pass1_kernel(
    const ushort* __restrict__ xf, const ushort* __restrict__ wf,
    const float* __restrict__ wsq, u64* __restrict__ keys) {
    __shared__ ushort A[128 * 32];   //  8 KB
    __shared__ ushort B[128 * 32];   //  8 KB
    __shared__ u64 red[128][2];      //  2 KB

    int m0 = blockIdx.x * 128;
    int k0 = blockIdx.y * 128;
    int tid = threadIdx.x, w = tid >> 6, lane = tid & 63;
    int wm = (w & 1) * 64, wn = (w >> 1) * 64;
    int lm = lane & 15, quad = lane >> 4;
    int srow = lane >> 2, scol = (lane & 3) * 8;

    f32x4 acc[4][4];
    #pragma unroll
    for (int mi = 0; mi < 4; ++mi)
        #pragma unroll
        for (int ni = 0; ni < 4; ++ni)
            acc[mi][ni] = (f32x4){0.f, 0.f, 0.f, 0.f};

    for (int kb = 0; kb < DIM; kb += 32) {
        size_t axoff = (size_t)(m0 + w * 32 + srow) * DIM + kb + scol;
        size_t bxoff = (size_t)(k0 + w * 32 + srow) * DIM + kb + scol;
        gload_lds16(xf + axoff,            &A[(w * 32) * 32]);
        gload_lds16(xf + axoff + 16 * DIM, &A[(w * 32 + 16) * 32]);
        gload_lds16(wf + bxoff,            &B[(w * 32) * 32]);
        gload_lds16(wf + bxoff + 16 * DIM, &B[(w * 32 + 16) * 32]);
        __syncthreads();
        half8 av[4], bv[4];
        #pragma unroll
        for (int mi = 0; mi < 4; ++mi)
            av[mi] = *(const half8*)&A[(wm + mi * 16 + lm) * 32 + quad * 8];
        #pragma unroll
        for (int ni = 0; ni < 4; ++ni)
            bv[ni] = *(const half8*)&B[(wn + ni * 16 + lm) * 32 + quad * 8];
        #pragma unroll
        for (int mi = 0; mi < 4; ++mi)
            #pragma unroll
            for (int ni = 0; ni < 4; ++ni)
                acc[mi][ni] = __builtin_amdgcn_mfma_f32_16x16x32_f16(
                    av[mi], bv[ni], acc[mi][ni], 0, 0, 0);
        __syncthreads();
    }

    float wsqv[4];
    #pragma unroll
    for (int ni = 0; ni < 4; ++ni) wsqv[ni] = wsq[k0 + wn + ni * 16 + lm];

    #pragma unroll
    for (int mi = 0; mi < 4; ++mi) {
        #pragma unroll
        for (int r = 0; r < 4; ++r) {
            u64 best = ~0ULL;
            #pragma unroll
            for (int ni = 0; ni < 4; ++ni) {
                float sc = fmaf(-2.0f, acc[mi][ni][r], wsqv[ni]);
                u64 p = ((u64)fmap(sc) << 32) |
                        (unsigned int)(k0 + wn + ni * 16 + lm);
                best = p < best ? p : best;
            }
            #pragma unroll
            for (int mask = 1; mask < 16; mask <<= 1) {
                u64 o = __shfl_xor(best, mask, 64);
                best = o < best ? o : best;
            }
            if (lm == 0) red[wm + mi * 16 + quad * 4 + r][w >> 1] = best;
        }
    }
    __syncthreads();
    if (tid < 128) {
        u64 a = red[tid][0], b = red[tid][1];
        atomicMin(&keys[m0 + tid], a < b ? a : b);
    }
}

// ---------------------------------------------------------------------------
// BMU pass 2: identical GEMM (bit-identical scores); select all k with
// score <= approxmin + MARGIN -> candidate list (hard-covers fp16 error).
__global__ __launch_bounds__(256) void bmu_pass2_kernel(
    const ushort* __restrict__ xf, const ushort* __restrict__ wf,
    const float* __restrict__ wsq, const u64* __restrict__ keys,
    u64* __restrict__ cand, unsigned int* __restrict__ cnt) {
    __shared__ ushort A[128 * 32];
    __shared__ ushort B[128 * 32];

    int m0 = blockIdx.x * 128;
    int k0 = blockIdx.y * 128;
    int tid = threadIdx.x, w = tid >> 6, lane = tid & 63;
    int wm = (w & 1) * 64, wn = (w >> 1) * 64;
    int lm = lane & 15, quad = lane >> 4;
    int srow = lane >> 2, scol = (lane & 3) * 8;

    f32x4 acc[4][4];
    #pragma unroll
    for (int mi = 0; mi < 4; ++mi)
        #pragma unroll
        for (int ni = 0; ni < 4; ++ni)
            acc[mi][ni] = (f32x4){0.f, 0.f, 0.f, 0.f};

    for (int kb = 0; kb < DIM; kb += 32) {
        size_t axoff = (size_t)(m0 + w * 32 + srow) * DIM + kb + scol;
        size_t bxoff = (size_t)(k0 + w * 32 + srow) * DIM + kb + scol;
        gload_lds16(xf + axoff,            &A[(w * 32) * 32]);
        gload_lds16(xf + axoff + 16 * DIM, &A[(w * 32 + 16) * 32]);
        gload_lds16(wf + bxoff,            &B[(w * 32) * 32]);
        gload_lds16(wf + bxoff + 16 * DIM, &B[(w * 32 + 16) * 32]);
        __syncthreads();
        half8 av[4], bv[4];
        #pragma unroll
        for (int mi = 0; mi < 4; ++mi)
            av[mi] = *(const half8*)&A[(wm + mi * 16 + lm) * 32 + quad * 8];
        #pragma unroll
        for (int ni = 0; ni < 4; ++ni)
            bv[ni] = *(const half8*)&B[(wn + ni * 16 + lm) * 32 + quad * 8];
        #pragma unroll
        for (int mi = 0; mi < 4; ++mi)
            #pragma unroll
            for (int ni = 0; ni < 4; ++ni)
                acc[mi][ni] = __builtin_amdgcn_mfma_f32_16x16x32_f16(
                    av[mi], bv[ni], acc[mi][ni], 0, 0, 0);
        __syncthreads();
    }

    float wsqv[4];
    #pragma unroll
    for (int ni = 0; ni < 4; ++ni) wsqv[ni] = wsq[k0 + wn + ni * 16 + lm];

    #pragma unroll
    for (int mi = 0; mi < 4; ++mi) {
        #pragma unroll
        for (int r = 0; r < 4; ++r) {
            int s = m0 + wm + mi * 16 + quad * 4 + r;
            float thr = unfmap((unsigned int)(keys[s] >> 32)) + MARGIN;
            #pragma unroll
            for (int ni = 0; ni < 4; ++ni) {
                float sc = fmaf(-2.0f, acc[mi][ni][r], wsqv[ni]);
                if (sc <= thr) {
                    unsigned int idx = atomicAdd(cnt, 1u);
                    if (idx < CAND_CAP)
                        cand[idx] = ((u64)(unsigned int)s << 32) |
                                    (unsigned int)(k0 + wn + ni * 16 + lm);
                }
            }
        }
    }
}

// ---------------------------------------------------------------------------
// BMU refine: exact f32 dist^2 per candidate, one wave per candidate (strided).
__global__ __launch_bounds__(256) void bmu_refine_kernel(
    const float* __restrict__ x, const float* __restrict__ w,
    const u64* __restrict__ cand, const unsigned int* __restrict__ cnt,
    u64* __restrict__ keys2) {
    int lane = threadIdx.x & 63;
    int wid = blockIdx.x * 4 + (threadIdx.x >> 6);
    unsigned int n = cnt[0];
    if (n > CAND_CAP) n = CAND_CAP;
    for (unsigned int c = wid; c < n; c += 128 * 4) {
        u64 e = cand[c];
        unsigned int s = (unsigned int)(e >> 32);
        unsigned int k = (unsigned int)e;
        float4 xv = *(const float4*)&x[(size_t)s * DIM + lane * 4];
        float4 wv = *(const float4*)&w[(size_t)k * DIM + lane * 4];
        float dx = xv.x - wv.x, dy = xv.y - wv.y;
        float dz = xv.z - wv.z, dw = xv.w - wv.w;
        float d = dx * dx + dy * dy + dz * dz + dw * dw;
        #pragma unroll
        for (int off = 32; off; off >>= 1) d += __shfl_down(d, off, 64);
        if (lane == 0)
            atomicMin(&keys2[s], ((u64)fmap(d) << 32) | k);
    }
}

// ---------------------------------------------------------------------------
// px/py Gaussian tables (lr cancels in numer/denom; dropped).
__global__ void pxy_kernel(const u64* __restrict__ keys,
                           const int* __restrict__ it_p,
                           float* __restrict__ px, float* __restrict__ py) {
    int b = blockIdx.x;
    int tid = threadIdx.x;
    unsigned int k = (unsigned int)(keys[b] & 0xFFFFFFFFu);
    int w0 = (int)(k >> 7), w1 = (int)(k & 127);
    float itf = (float)it_p[0];
    const float START_SIGMA = 64.0f;
    const float TAU = (float)(20.0 / 4.1588830833596715);  // 20 / ln(64)
    float sigma = START_SIGMA * expf(-itf / TAU);
    float d2 = 2.0f * sigma * sigma;
    if (tid < 128) {
        float diff = (float)(tid - w0);
        px[b * 128 + tid] = expf(-(diff * diff) / d2);
    } else {
        int j = tid - 128;
        float diff = (float)(j - w1);
        py[b * 128 + j] = expf(-(diff * diff) / d2);
    }
}

// ---------------------------------------------------------------------------
// Transpose px AND py [8192][128] -> [128][8192] in one launch (blockIdx.z).
__global__ void tpose2_kernel(const float* __restrict__ px, const float* __restrict__ py,
                              float* __restrict__ pxT, float* __restrict__ pyT) {
    __shared__ float tile[64][68];
    const float* in = blockIdx.z ? py : px;
    float* outT = blockIdx.z ? pyT : pxT;
    int b0 = blockIdx.x * 64;
    int c0 = blockIdx.y * 64;
    int t = threadIdx.x;
    int rr = t >> 4, seg = t & 15;
    #pragma unroll
    for (int p = 0; p < 4; ++p) {
        int row = rr + p * 16;
        float4 v = *(const float4*)&in[(size_t)(b0 + row) * 128 + c0 + seg * 4];
        tile[seg * 4 + 0][row] = v.x; tile[seg * 4 + 1][row] = v.y;
        tile[seg * 4 + 2][row] = v.z; tile[seg * 4 + 3][row] = v.w;
    }
    __syncthreads();
    #pragma unroll
    for (int p = 0; p < 4; ++p) {
        int crow = rr + p * 16;
        *(float4*)&outT[(size_t)(c0 + crow) * BS + b0 + seg * 4] =
            *(float4*)&tile[crow][seg * 4];
    }
}

// ---------------------------------------------------------------------------
// denom[i][j] = sum_b px[b][i]*py[b][j] as block-parallel outer product.
__global__ __launch_bounds__(256) void denom_op_kernel(
    const float* __restrict__ px, const float* __restrict__ py,
    float* __restrict__ denom) {
    __shared__ float pxs[64][128];   // 32 KB
    __shared__ float pys[64][128];   // 32 KB
    int b0 = blockIdx.x * 64;
    int tid = threadIdx.x;
    #pragma unroll
    for (int q = 0; q < 8; ++q) {
        int idx = q * 256 + tid;
        int row = idx >> 5;
        int col = (idx & 31) * 4;
        *(float4*)&pxs[row][col] = *(const float4*)&px[(size_t)(b0 + row) * 128 + col];
        *(float4*)&pys[row][col] = *(const float4*)&py[(size_t)(b0 + row) * 128 + col];
    }
    __syncthreads();
    int ig = tid >> 4, jg = tid & 15;
    float acc[8][8] = {};
    for (int b = 0; b < 64; ++b) {
        float pv[8], qv[8];
        *(float4*)&pv[0] = *(float4*)&pxs[b][ig * 8];
        *(float4*)&pv[4] = *(float4*)&pxs[b][ig * 8 + 4];
        *(float4*)&qv[0] = *(float4*)&pys[b][jg * 8];
        *(float4*)&qv[4] = *(float4*)&pys[b][jg * 8 + 4];
        #pragma unroll
        for (int ii = 0; ii < 8; ++ii)
            #pragma unroll
            for (int jj = 0; jj < 8; ++jj)
                acc[ii][jj] = fmaf(pv[ii], qv[jj], acc[ii][jj]);
    }
    #pragma unroll
    for (int ii = 0; ii < 8; ++ii)
        #pragma unroll
        for (int jj = 0; jj < 8; ++jj)
            atomicAdd(&denom[(ig * 8 + ii) * 128 + jg * 8 + jj], acc[ii][jj]);
}

// ---------------------------------------------------------------------------
// numer = P^T X via fp16 MFMA.  Tile M=128 (j), N=128 (d), K=2048.
// Grid (128 i x 2 d-tiles x 4 ksplits); A computed at staging (p=px*py -> fp16),
// B = xfT via global_load_lds; atomicAdd partials into zeroed out.
__global__ __launch_bounds__(256) void numer_mfma_kernel(
    const float* __restrict__ pxT, const float* __restrict__ pyT,
    const ushort* __restrict__ xfT, float* __restrict__ out) {
    __shared__ ushort Alds[128 * 32];   //  8 KB
    __shared__ ushort Blds[128 * 32];   //  8 KB

    int i   = blockIdx.x;
    int d0  = blockIdx.y * 128;
    int ks  = blockIdx.z;
    int tid = threadIdx.x;
    int w = tid >> 6, lane = tid & 63;
    int wm = (w & 1) * 64, wn = (w >> 1) * 64;
    int lm = lane & 15, quad = lane >> 4;

    f32x4 acc[4][4];
    #pragma unroll
    for (int mi = 0; mi < 4; ++mi)
        #pragma unroll
        for (int ni = 0; ni < 4; ++ni)
            acc[mi][ni] = (f32x4){0.f, 0.f, 0.f, 0.f};

    const float* pxrow = pxT + (size_t)i * BS;
    int aj0 = tid >> 2;
    int ab  = (tid & 3) * 8;
    int brl = w * 32 + (lane >> 2);
    int bcl = (lane & 3) * 8;

    for (int kb = ks * 2048; kb < ks * 2048 + 2048; kb += 32) {
        gload_lds16(xfT + (size_t)(d0 + brl) * BS + kb + bcl,
                    &Blds[(w * 32) * 32]);
        gload_lds16(xfT + (size_t)(d0 + brl + 16) * BS + kb + bcl,
                    &Blds[(w * 32 + 16) * 32]);
        #pragma unroll
        for (int ph = 0; ph < 2; ++ph) {
            int j = aj0 + ph * 64;
            const float* pyr = pyT + (size_t)j * BS + kb + ab;
            float4 y0 = *(const float4*)pyr;
            float4 y1 = *(const float4*)(pyr + 4);
            float4 x0 = *(const float4*)&pxrow[kb + ab];
            float4 x1 = *(const float4*)&pxrow[kb + ab + 4];
            union { ushort u[8]; float4 v; } pk;
            pk.u[0] = f2h(y0.x * x0.x); pk.u[1] = f2h(y0.y * x0.y);
            pk.u[2] = f2h(y0.z * x0.z); pk.u[3] = f2h(y0.w * x0.w);
            pk.u[4] = f2h(y1.x * x1.x); pk.u[5] = f2h(y1.y * x1.y);
            pk.u[6] = f2h(y1.z * x1.z); pk.u[7] = f2h(y1.w * x1.w);
            *(float4*)&Alds[j * 32 + ab] = pk.v;
        }
        __syncthreads();
        half8 af[4], bg[4];
        #pragma unroll
        for (int mi = 0; mi < 4; ++mi)
            af[mi] = *(const half8*)&Alds[(wm + mi * 16 + lm) * 32 + quad * 8];
        #pragma unroll
        for (int ni = 0; ni < 4; ++ni)
            bg[ni] = *(const half8*)&Blds[(wn + ni * 16 + lm) * 32 + quad * 8];
        #pragma unroll
        for (int mi = 0; mi < 4; ++mi)
            #pragma unroll
            for (int ni = 0; ni < 4; ++ni)
                acc[mi][ni] = __builtin_amdgcn_mfma_f32_16x16x32_f16(
                    af[mi], bg[ni], acc[mi][ni], 0, 0, 0);
        __syncthreads();
    }
    #pragma unroll
    for (int mi = 0; mi < 4; ++mi) {
        int j = i * 128 + wm + mi * 16 + quad * 4;
        #pragma unroll
        for (int ni = 0; ni < 4; ++ni) {
            int d = d0 + wn + ni * 16 + lm;
            float* op = &out[(size_t)j * DIM + d];
            atomicAdd(op + 0 * DIM, acc[mi][ni][0]);
            atomicAdd(op + 1 * DIM, acc[mi][ni][1]);
            atomicAdd(op + 2 * DIM, acc[mi][ni][2]);
            atomicAdd(op + 3 * DIM, acc[mi][ni][3]);
        }
    }
}

// ---------------------------------------------------------------------------
// finalize: out = denom!=0 ? out/denom : w
__global__ void finalize_kernel(float* __restrict__ out, const float* __restrict__ denom,
                                const float* __restrict__ w) {
    int idx = blockIdx.x * 256 + threadIdx.x;
    int e = idx * 4;
    int k = e >> 8;
    float dv = denom[k];
    float4 nv = *(float4*)&out[e];
    float4 wv = *(const float4*)&w[e];
    float4 r;
    if (dv != 0.0f) {
        r.x = nv.x / dv; r.y = nv.y / dv; r.z = nv.z / dv; r.w = nv.w / dv;
    } else {
        r = wv;
    }
    *(float4*)&out[e] = r;
}

// ---------------------------------------------------------------------------
extern "C" void kernel_launch(void* const* d_in, const int* in_sizes, int n_in,
                              void* d_out, int out_size, void* d_ws, size_t ws_size,
                              hipStream_t stream) {
    const float* data = (const float*)d_in[0];   // [8192, 256] f32
    const float* w    = (const float*)d_in[1];   // [128,128,256] f32
    const int*   itp  = (const int*)d_in[2];     // scalar
    float* out = (float*)d_out;                  // [128,128,256] f32

    char* ws = (char*)d_ws;
    size_t off = 0;
    float*        wsq   = (float*)(ws + off);        off += 65536;     //  64 KB
    u64*          keys  = (u64*)(ws + off);          off += 65536;     //  64 KB (approx)
    u64*          keys2 = (u64*)(ws + off);          off += 65536;     //  64 KB (exact)
    unsigned int* cnt   = (unsigned int*)(ws + off); off += 65536;     //  64 KB
    float*        px    = (float*)(ws + off);        off += 4194304;   //   4 MB [b][i]
    float*        py    = (float*)(ws + off);        off += 4194304;   //   4 MB [b][j]
    float*        denom = (float*)(ws + off);        off += 65536;     //  64 KB
    float*        pxT   = (float*)(ws + off);        off += 4194304;   //   4 MB [i][b]
    float*        pyT   = (float*)(ws + off);        off += 4194304;   //   4 MB [j][b]
    ushort*       xf    = (ushort*)(ws + off);       off += 4194304;   //   4 MB [b][d] fp16
    ushort*       xfT   = (ushort*)(ws + off);       off += 4194304;   //   4 MB [d][b] fp16
    ushort*       wf    = (ushort*)(ws + off);       off += 8388608;   //   8 MB [k][d] fp16
    u64*          cand  = (u64*)(ws + off);          off += 1048576;   //   1 MB

    zero_out_kernel<<<KTOT * DIM / 1024, 256, 0, stream>>>(out);
    setup_kernel<<<KTOT / 256, 256, 0, stream>>>(denom, keys, keys2, cnt);
    cvt_x_kernel<<<dim3(BS / 64, DIM / 64), 256, 0, stream>>>(data, xf, xfT);
    cvt_w_f16_kernel<<<KTOT / 4, 256, 0, stream>>>(w, wf, wsq);
    bmu_pass1_kernel<<<dim3(64, 128), 256, 0, stream>>>(xf, wf, wsq, keys);
    bmu_pass2_kernel<<<dim3(64, 128), 256, 0, stream>>>(xf, wf, wsq, keys, cand, cnt);
    bmu_refine_kernel<<<128, 256, 0, stream>>>(data, w, cand, cnt, keys2);
    pxy_kernel<<<BS, 256, 0, stream>>>(keys2, itp, px, py);
    tpose2_kernel<<<dim3(BS / 64, 2, 2), 256, 0, stream>>>(px, py, pxT, pyT);
    denom_op_kernel<<<128, 256, 0, stream>>>(px, py, denom);
    numer_mfma_kernel<<<dim3(128, 2, 4), 256, 0, stream>>>(pxT, pyT, xfT, out);
    finalize_kernel<<<KTOT * DIM / 1024, 256, 0, stream>>>(out, denom, w);
}

// Round 7
// 453.748 us; speedup vs baseline: 1.7054x; 1.3758x over previous
//
#include <hip/hip_runtime.h>
#include <hip/hip_fp16.h>

// Problem constants
#define BS    8192
#define DIM   256
#define KTOT  16384      // 128x128 codebook
#define CAND_CAP 131072
#define MARGIN 1.0f

typedef __attribute__((ext_vector_type(8))) _Float16 half8;
typedef __attribute__((ext_vector_type(4))) float f32x4;
typedef unsigned long long u64;

__device__ inline ushort f2h(float f) { return __half_as_ushort(__float2half(f)); }

// async global->LDS, 16B per lane; lds dest = wave-uniform base + lane*16
__device__ inline void gload_lds16(const void* g, void* l) {
    __builtin_amdgcn_global_load_lds(
        (const __attribute__((address_space(1))) unsigned int*)g,
        (__attribute__((address_space(3))) unsigned int*)l, 16, 0, 0);
}

// order-preserving f32 -> u32 map (ascending) and inverse
__device__ inline unsigned int fmap(float f) {
    unsigned int b = __float_as_uint(f);
    return (b & 0x80000000u) ? ~b : (b | 0x80000000u);
}
__device__ inline float unfmap(unsigned int m) {
    return (m & 0x80000000u) ? __uint_as_float(m & 0x7FFFFFFFu)
                             : __uint_as_float(~m);
}

// ---------------------------------------------------------------------------
// setup: G[i][j]=exp(-(i-j)^2/d2) (128x128), zero cntf, init keys, zero cnt.
__global__ void setup_kernel(float* __restrict__ G, float* __restrict__ cntf,
                             u64* __restrict__ keys, u64* __restrict__ keys2,
                             unsigned int* __restrict__ cnt, const int* __restrict__ itp) {
    int idx = blockIdx.x * 256 + threadIdx.x;
    float itf = (float)itp[0];
    const float START_SIGMA = 64.0f;
    const float TAU = (float)(20.0 / 4.1588830833596715);  // 20 / ln(64)
    float sigma = START_SIGMA * expf(-itf / TAU);
    float d2 = 2.0f * sigma * sigma;
    int i = idx >> 7, j = idx & 127;
    float diff = (float)(i - j);
    G[idx] = expf(-(diff * diff) / d2);
    cntf[idx] = 0.f;
    if (idx < BS) { keys[idx] = ~0ULL; keys2[idx] = ~0ULL; }
    if (idx == 0) cnt[0] = 0u;
}

__global__ void zero_S_kernel(float* __restrict__ S) {
    int idx = blockIdx.x * 256 + threadIdx.x;
    *(float4*)&S[(size_t)idx * 4] = make_float4(0.f, 0.f, 0.f, 0.f);
}

// data -> fp16 row-major
__global__ void cvt_x_f16_kernel(const float* __restrict__ x, ushort* __restrict__ xf) {
    int idx = blockIdx.x * 256 + threadIdx.x;
    float4 v = *(const float4*)&x[(size_t)idx * 4];
    ushort4 h;
    h.x = f2h(v.x); h.y = f2h(v.y); h.z = f2h(v.z); h.w = f2h(v.w);
    *(ushort4*)&xf[(size_t)idx * 4] = h;
}

// w -> fp16 + wsq, one wave per row (4 rows/block).
__global__ void cvt_w_f16_kernel(const float* __restrict__ w, ushort* __restrict__ wf,
                                 float* __restrict__ wsq) {
    int wid = threadIdx.x >> 6, lane = threadIdx.x & 63;
    size_t row = blockIdx.x * 4 + wid;
    float4 v = *(const float4*)&w[row * DIM + lane * 4];
    ushort4 h;
    h.x = f2h(v.x); h.y = f2h(v.y); h.z = f2h(v.z); h.w = f2h(v.w);
    *(ushort4*)&wf[row * DIM + lane * 4] = h;
    float s = v.x * v.x + v.y * v.y + v.z * v.z + v.w * v.w;
    #pragma unroll
    for (int off = 32; off; off >>= 1) s += __shfl_down(s, off, 64);
    if (lane == 0) wsq[row] = s;
}

// ---------------------------------------------------------------------------
// BMU pass 1: fp16 GEMM, tile 128 samples x 128 k; approx argmin via atomicMin.
__global__ __launch_bounds__(256) void bmu_pass1_kernel(
    const ushort* __restrict__ xf, const ushort* __restrict__ wf,
    const float* __restrict__ wsq, u64* __restrict__ keys) {
    __shared__ ushort A[128 * 32];
    __shared__ ushort B[128 * 32];
    __shared__ u64 red[128][2];

    int m0 = blockIdx.x * 128;
    int k0 = blockIdx.y * 128;
    int tid = threadIdx.x, w = tid >> 6, lane = tid & 63;
    int wm = (w & 1) * 64, wn = (w >> 1) * 64;
    int lm = lane & 15, quad = lane >> 4;
    int srow = lane >> 2, scol = (lane & 3) * 8;

    f32x4 acc[4][4];
    #pragma unroll
    for (int mi = 0; mi < 4; ++mi)
        #pragma unroll
        for (int ni = 0; ni < 4; ++ni)
            acc[mi][ni] = (f32x4){0.f, 0.f, 0.f, 0.f};

    for (int kb = 0; kb < DIM; kb += 32) {
        size_t axoff = (size_t)(m0 + w * 32 + srow) * DIM + kb + scol;
        size_t bxoff = (size_t)(k0 + w * 32 + srow) * DIM + kb + scol;
        gload_lds16(xf + axoff,            &A[(w * 32) * 32]);
        gload_lds16(xf + axoff + 16 * DIM, &A[(w * 32 + 16) * 32]);
        gload_lds16(wf + bxoff,            &B[(w * 32) * 32]);
        gload_lds16(wf + bxoff + 16 * DIM, &B[(w * 32 + 16) * 32]);
        __syncthreads();
        half8 av[4], bv[4];
        #pragma unroll
        for (int mi = 0; mi < 4; ++mi)
            av[mi] = *(const half8*)&A[(wm + mi * 16 + lm) * 32 + quad * 8];
        #pragma unroll
        for (int ni = 0; ni < 4; ++ni)
            bv[ni] = *(const half8*)&B[(wn + ni * 16 + lm) * 32 + quad * 8];
        #pragma unroll
        for (int mi = 0; mi < 4; ++mi)
            #pragma unroll
            for (int ni = 0; ni < 4; ++ni)
                acc[mi][ni] = __builtin_amdgcn_mfma_f32_16x16x32_f16(
                    av[mi], bv[ni], acc[mi][ni], 0, 0, 0);
        __syncthreads();
    }

    float wsqv[4];
    #pragma unroll
    for (int ni = 0; ni < 4; ++ni) wsqv[ni] = wsq[k0 + wn + ni * 16 + lm];

    #pragma unroll
    for (int mi = 0; mi < 4; ++mi) {
        #pragma unroll
        for (int r = 0; r < 4; ++r) {
            u64 best = ~0ULL;
            #pragma unroll
            for (int ni = 0; ni < 4; ++ni) {
                float sc = fmaf(-2.0f, acc[mi][ni][r], wsqv[ni]);
                u64 p = ((u64)fmap(sc) << 32) |
                        (unsigned int)(k0 + wn + ni * 16 + lm);
                best = p < best ? p : best;
            }
            #pragma unroll
            for (int mask = 1; mask < 16; mask <<= 1) {
                u64 o = __shfl_xor(best, mask, 64);
                best = o < best ? o : best;
            }
            if (lm == 0) red[wm + mi * 16 + quad * 4 + r][w >> 1] = best;
        }
    }
    __syncthreads();
    if (tid < 128) {
        u64 a = red[tid][0], b = red[tid][1];
        atomicMin(&keys[m0 + tid], a < b ? a : b);
    }
}

// ---------------------------------------------------------------------------
// BMU pass 2: identical GEMM; emit all k with score <= approxmin + MARGIN.
__global__ __launch_bounds__(256) void bmu_pass2_kernel(
    const ushort* __restrict__ xf, const ushort* __restrict__ wf,
    const float* __restrict__ wsq, const u64* __restrict__ keys,
    u64* __restrict__ cand, unsigned int* __restrict__ cnt) {
    __shared__ ushort A[128 * 32];
    __shared__ ushort B[128 * 32];

    int m0 = blockIdx.x * 128;
    int k0 = blockIdx.y * 128;
    int tid = threadIdx.x, w = tid >> 6, lane = tid & 63;
    int wm = (w & 1) * 64, wn = (w >> 1) * 64;
    int lm = lane & 15, quad = lane >> 4;
    int srow = lane >> 2, scol = (lane & 3) * 8;

    f32x4 acc[4][4];
    #pragma unroll
    for (int mi = 0; mi < 4; ++mi)
        #pragma unroll
        for (int ni = 0; ni < 4; ++ni)
            acc[mi][ni] = (f32x4){0.f, 0.f, 0.f, 0.f};

    for (int kb = 0; kb < DIM; kb += 32) {
        size_t axoff = (size_t)(m0 + w * 32 + srow) * DIM + kb + scol;
        size_t bxoff = (size_t)(k0 + w * 32 + srow) * DIM + kb + scol;
        gload_lds16(xf + axoff,            &A[(w * 32) * 32]);
        gload_lds16(xf + axoff + 16 * DIM, &A[(w * 32 + 16) * 32]);
        gload_lds16(wf + bxoff,            &B[(w * 32) * 32]);
        gload_lds16(wf + bxoff + 16 * DIM, &B[(w * 32 + 16) * 32]);
        __syncthreads();
        half8 av[4], bv[4];
        #pragma unroll
        for (int mi = 0; mi < 4; ++mi)
            av[mi] = *(const half8*)&A[(wm + mi * 16 + lm) * 32 + quad * 8];
        #pragma unroll
        for (int ni = 0; ni < 4; ++ni)
            bv[ni] = *(const half8*)&B[(wn + ni * 16 + lm) * 32 + quad * 8];
        #pragma unroll
        for (int mi = 0; mi < 4; ++mi)
            #pragma unroll
            for (int ni = 0; ni < 4; ++ni)
                acc[mi][ni] = __builtin_amdgcn_mfma_f32_16x16x32_f16(
                    av[mi], bv[ni], acc[mi][ni], 0, 0, 0);
        __syncthreads();
    }

    float wsqv[4];
    #pragma unroll
    for (int ni = 0; ni < 4; ++ni) wsqv[ni] = wsq[k0 + wn + ni * 16 + lm];

    #pragma unroll
    for (int mi = 0; mi < 4; ++mi) {
        #pragma unroll
        for (int r = 0; r < 4; ++r) {
            int s = m0 + wm + mi * 16 + quad * 4 + r;
            float thr = unfmap((unsigned int)(keys[s] >> 32)) + MARGIN;
            #pragma unroll
            for (int ni = 0; ni < 4; ++ni) {
                float sc = fmaf(-2.0f, acc[mi][ni][r], wsqv[ni]);
                if (sc <= thr) {
                    unsigned int idx = atomicAdd(cnt, 1u);
                    if (idx < CAND_CAP)
                        cand[idx] = ((u64)(unsigned int)s << 32) |
                                    (unsigned int)(k0 + wn + ni * 16 + lm);
                }
            }
        }
    }
}

// ---------------------------------------------------------------------------
// BMU refine: exact f32 dist^2 per candidate, one wave per candidate.
__global__ __launch_bounds__(256) void bmu_refine_kernel(
    const float* __restrict__ x, const float* __restrict__ w,
    const u64* __restrict__ cand, const unsigned int* __restrict__ cnt,
    u64* __restrict__ keys2) {
    int lane = threadIdx.x & 63;
    int wid = blockIdx.x * 4 + (threadIdx.x >> 6);
    unsigned int n = cnt[0];
    if (n > CAND_CAP) n = CAND_CAP;
    for (unsigned int c = wid; c < n; c += 256 * 4) {
        u64 e = cand[c];
        unsigned int s = (unsigned int)(e >> 32);
        unsigned int k = (unsigned int)e;
        float4 xv = *(const float4*)&x[(size_t)s * DIM + lane * 4];
        float4 wv = *(const float4*)&w[(size_t)k * DIM + lane * 4];
        float dx = xv.x - wv.x, dy = xv.y - wv.y;
        float dz = xv.z - wv.z, dw = xv.w - wv.w;
        float d = dx * dx + dy * dy + dz * dz + dw * dw;
        #pragma unroll
        for (int off = 32; off; off >>= 1) d += __shfl_down(d, off, 64);
        if (lane == 0)
            atomicMin(&keys2[s], ((u64)fmap(d) << 32) | k);
    }
}

// ---------------------------------------------------------------------------
// scatter: S[bmu(s)][:] += x[s][:], cntf[bmu(s)] += 1.  One wave per sample.
__global__ __launch_bounds__(256) void scatter_kernel(
    const float* __restrict__ x, const u64* __restrict__ keys2,
    float* __restrict__ S, float* __restrict__ cntf) {
    int lane = threadIdx.x & 63;
    int s = blockIdx.x * 4 + (threadIdx.x >> 6);
    unsigned int k = (unsigned int)keys2[s];
    float4 xv = *(const float4*)&x[(size_t)s * DIM + lane * 4];
    float* Sp = &S[(size_t)k * DIM + lane * 4];
    atomicAdd(Sp + 0, xv.x);
    atomicAdd(Sp + 1, xv.y);
    atomicAdd(Sp + 2, xv.z);
    atomicAdd(Sp + 3, xv.w);
    if (lane == 0) atomicAdd(&cntf[k], 1.0f);
}

// ---------------------------------------------------------------------------
// gemm1: T[i][m] = sum_a G[i][a] * Sf[a][m], m in [0,32768), f32.
// Grid 512 blocks (64-col n-tiles); 256 thr = 16 ng x 16 ig; 2 i-passes.
__global__ __launch_bounds__(256) void gemm1_kernel(
    const float* __restrict__ G, const float* __restrict__ S, float* __restrict__ T) {
    __shared__ float Sl[128 * 68];   // 34.8 KB, pad 68
    int n0 = blockIdx.x * 64;
    int tid = threadIdx.x;
    #pragma unroll
    for (int q = 0; q < 8; ++q) {
        int idx = q * 256 + tid;
        int row = idx >> 4, c4 = (idx & 15) * 4;
        *(float4*)&Sl[row * 68 + c4] = *(const float4*)&S[(size_t)row * 32768 + n0 + c4];
    }
    __syncthreads();
    int ng = tid & 15, ig = tid >> 4;
    for (int pass = 0; pass < 2; ++pass) {
        int ibase = pass * 64 + ig * 4;
        float acc[4][4] = {};
        for (int a = 0; a < 128; ++a) {
            float4 sv = *(const float4*)&Sl[a * 68 + ng * 4];
            #pragma unroll
            for (int ii = 0; ii < 4; ++ii) {
                float g = G[(ibase + ii) * 128 + a];
                acc[ii][0] = fmaf(g, sv.x, acc[ii][0]);
                acc[ii][1] = fmaf(g, sv.y, acc[ii][1]);
                acc[ii][2] = fmaf(g, sv.z, acc[ii][2]);
                acc[ii][3] = fmaf(g, sv.w, acc[ii][3]);
            }
        }
        #pragma unroll
        for (int ii = 0; ii < 4; ++ii)
            *(float4*)&T[(size_t)(ibase + ii) * 32768 + n0 + ng * 4] =
                *(float4*)&acc[ii][0];
    }
}

// ---------------------------------------------------------------------------
// denom stage 1: M1[a][j] = sum_b2 cntf[a][b2] * G[b2][j]   (G symmetric)
__global__ void denom_s1_kernel(const float* __restrict__ cntf, const float* __restrict__ G,
                                float* __restrict__ M1) {
    int a = blockIdx.x, j = threadIdx.x;
    float acc = 0.f;
    for (int b2 = 0; b2 < 128; ++b2)
        acc = fmaf(cntf[a * 128 + b2], G[b2 * 128 + j], acc);
    M1[a * 128 + j] = acc;
}

// denom stage 2: denom[i][j] = sum_a G[i][a] * M1[a][j]
__global__ void denom_s2_kernel(const float* __restrict__ G, const float* __restrict__ M1,
                                float* __restrict__ denom) {
    int i = blockIdx.x, j = threadIdx.x;
    float acc = 0.f;
    for (int a = 0; a < 128; ++a)
        acc = fmaf(G[i * 128 + a], M1[a * 128 + j], acc);
    denom[i * 128 + j] = acc;
}

// ---------------------------------------------------------------------------
// gemm2 + finalize: out[i][j][d] = (sum_b2 G[j][b2] T[i][b2*256+d]) / denom[i][j]
// (or w if denom==0).  Grid (128 i x 4 d-quarters); 256 thr = 16 dg x 16 jg.
__global__ __launch_bounds__(256) void gemm2_fin_kernel(
    const float* __restrict__ G, const float* __restrict__ T,
    const float* __restrict__ denom, const float* __restrict__ w,
    float* __restrict__ out) {
    __shared__ float Tl[128 * 68];   // 34.8 KB
    int i = blockIdx.x, dq = blockIdx.y;
    int tid = threadIdx.x;
    #pragma unroll
    for (int q = 0; q < 8; ++q) {
        int idx = q * 256 + tid;
        int row = idx >> 4, c4 = (idx & 15) * 4;
        *(float4*)&Tl[row * 68 + c4] =
            *(const float4*)&T[(size_t)i * 32768 + row * 256 + dq * 64 + c4];
    }
    __syncthreads();
    int dg = tid & 15, jg = tid >> 4;
    for (int pass = 0; pass < 2; ++pass) {
        int jbase = pass * 64 + jg * 4;
        float acc[4][4] = {};
        for (int b2 = 0; b2 < 128; ++b2) {
            float4 tv = *(const float4*)&Tl[b2 * 68 + dg * 4];
            #pragma unroll
            for (int jj = 0; jj < 4; ++jj) {
                float g = G[(jbase + jj) * 128 + b2];
                acc[jj][0] = fmaf(g, tv.x, acc[jj][0]);
                acc[jj][1] = fmaf(g, tv.y, acc[jj][1]);
                acc[jj][2] = fmaf(g, tv.z, acc[jj][2]);
                acc[jj][3] = fmaf(g, tv.w, acc[jj][3]);
            }
        }
        #pragma unroll
        for (int jj = 0; jj < 4; ++jj) {
            int j = jbase + jj;
            float dv = denom[i * 128 + j];
            size_t e = (size_t)(i * 128 + j) * DIM + dq * 64 + dg * 4;
            float4 r;
            if (dv != 0.0f) {
                float inv = 1.0f / dv;
                r.x = acc[jj][0] * inv; r.y = acc[jj][1] * inv;
                r.z = acc[jj][2] * inv; r.w = acc[jj][3] * inv;
            } else {
                r = *(const float4*)&w[e];
            }
            *(float4*)&out[e] = r;
        }
    }
}

// ---------------------------------------------------------------------------
extern "C" void kernel_launch(void* const* d_in, const int* in_sizes, int n_in,
                              void* d_out, int out_size, void* d_ws, size_t ws_size,
                              hipStream_t stream) {
    const float* data = (const float*)d_in[0];   // [8192, 256] f32
    const float* w    = (const float*)d_in[1];   // [128,128,256] f32
    const int*   itp  = (const int*)d_in[2];     // scalar
    float* out = (float*)d_out;                  // [128,128,256] f32

    char* ws = (char*)d_ws;
    size_t off = 0;
    float*        wsq   = (float*)(ws + off);        off += 65536;     //  64 KB
    u64*          keys  = (u64*)(ws + off);          off += 65536;     //  64 KB (approx)
    u64*          keys2 = (u64*)(ws + off);          off += 65536;     //  64 KB (exact)
    unsigned int* cnt   = (unsigned int*)(ws + off); off += 65536;     //  64 KB
    float*        G     = (float*)(ws + off);        off += 65536;     //  64 KB [128][128]
    float*        cntf  = (float*)(ws + off);        off += 65536;     //  64 KB [a][b2]
    float*        M1    = (float*)(ws + off);        off += 65536;     //  64 KB
    float*        denom = (float*)(ws + off);        off += 65536;     //  64 KB
    ushort*       xf    = (ushort*)(ws + off);       off += 4194304;   //   4 MB fp16
    ushort*       wf    = (ushort*)(ws + off);       off += 8388608;   //   8 MB fp16
    u64*          cand  = (u64*)(ws + off);          off += 1048576;   //   1 MB
    float*        S     = (float*)(ws + off);        off += 16777216;  //  16 MB [c][d]
    float*        T     = (float*)(ws + off);        off += 16777216;  //  16 MB [i][32768]

    setup_kernel<<<64, 256, 0, stream>>>(G, cntf, keys, keys2, cnt, itp);
    zero_S_kernel<<<4096, 256, 0, stream>>>(S);
    cvt_x_f16_kernel<<<BS * DIM / 1024, 256, 0, stream>>>(data, xf);
    cvt_w_f16_kernel<<<KTOT / 4, 256, 0, stream>>>(w, wf, wsq);
    bmu_pass1_kernel<<<dim3(64, 128), 256, 0, stream>>>(xf, wf, wsq, keys);
    bmu_pass2_kernel<<<dim3(64, 128), 256, 0, stream>>>(xf, wf, wsq, keys, cand, cnt);
    bmu_refine_kernel<<<256, 256, 0, stream>>>(data, w, cand, cnt, keys2);
    scatter_kernel<<<BS / 4, 256, 0, stream>>>(data, keys2, S, cntf);
    gemm1_kernel<<<512, 256, 0, stream>>>(G, S, T);
    denom_s1_kernel<<<128, 128, 0, stream>>>(cntf, G, M1);
    denom_s2_kernel<<<128, 128, 0, stream>>>(G, M1, denom);
    gemm2_fin_kernel<<<dim3(128, 4), 256, 0, stream>>>(G, T, denom, w, out);
}

// Round 8
// 402.580 us; speedup vs baseline: 1.9222x; 1.1271x over previous
//
#include <hip/hip_runtime.h>
#include <hip/hip_fp16.h>

// Problem constants
#define BS    8192
#define DIM   256
#define KTOT  16384      // 128x128 codebook
#define CAND_CAP 131072
#define MARGIN 1.0f

typedef __attribute__((ext_vector_type(8))) _Float16 half8;
typedef __attribute__((ext_vector_type(4))) float f32x4;
typedef unsigned long long u64;

__device__ inline ushort f2h(float f) { return __half_as_ushort(__float2half(f)); }

// async global->LDS, 16B per lane; lds dest = wave-uniform base + lane*16
__device__ inline void gload_lds16(const void* g, void* l) {
    __builtin_amdgcn_global_load_lds(
        (const __attribute__((address_space(1))) unsigned int*)g,
        (__attribute__((address_space(3))) unsigned int*)l, 16, 0, 0);
}

// order-preserving f32 -> u32 map (ascending) and inverse
__device__ inline unsigned int fmap(float f) {
    unsigned int b = __float_as_uint(f);
    return (b & 0x80000000u) ? ~b : (b | 0x80000000u);
}
__device__ inline float unfmap(unsigned int m) {
    return (m & 0x80000000u) ? __uint_as_float(m & 0x7FFFFFFFu)
                             : __uint_as_float(~m);
}

// ---------------------------------------------------------------------------
// setup: zero S (16 MB), G table, zero cntf, init keys(u32)/keys2(u64), cnt.
__global__ void setup_all_kernel(float* __restrict__ S, float* __restrict__ G,
                                 float* __restrict__ cntf, unsigned int* __restrict__ keys,
                                 u64* __restrict__ keys2, unsigned int* __restrict__ cnt,
                                 const int* __restrict__ itp) {
    int idx = blockIdx.x * 256 + threadIdx.x;
    *(float4*)&S[(size_t)idx * 4] = make_float4(0.f, 0.f, 0.f, 0.f);
    if (idx < KTOT) {
        float itf = (float)itp[0];
        const float START_SIGMA = 64.0f;
        const float TAU = (float)(20.0 / 4.1588830833596715);  // 20 / ln(64)
        float sigma = START_SIGMA * expf(-itf / TAU);
        float d2 = 2.0f * sigma * sigma;
        int i = idx >> 7, j = idx & 127;
        float diff = (float)(i - j);
        G[idx] = expf(-(diff * diff) / d2);
        cntf[idx] = 0.f;
    }
    if (idx < BS) { keys[idx] = 0xFFFFFFFFu; keys2[idx] = ~0ULL; }
    if (idx == 0) cnt[0] = 0u;
}

// ---------------------------------------------------------------------------
// x,w -> fp16 with XOR-swizzled 32-half windows (block c -> c ^ ((row>>1)&3)),
// + wsq for w rows.  One wave per row; rows [0,BS) are x, [BS, BS+KTOT) are w.
__global__ void cvt_all_kernel(const float* __restrict__ x, const float* __restrict__ w,
                               ushort* __restrict__ xf, ushort* __restrict__ wf,
                               float* __restrict__ wsq) {
    int wid = threadIdx.x >> 6, lane = threadIdx.x & 63;
    int row = blockIdx.x * 4 + wid;
    int h = lane * 4;                      // half index 0..255
    int window = h >> 5, c = (h >> 3) & 3, off = h & 7;
    if (row < BS) {
        int swpos = (window << 5) + (((c ^ ((row >> 1) & 3)) << 3)) + off;
        float4 v = *(const float4*)&x[(size_t)row * DIM + h];
        ushort4 hv;
        hv.x = f2h(v.x); hv.y = f2h(v.y); hv.z = f2h(v.z); hv.w = f2h(v.w);
        *(ushort4*)&xf[(size_t)row * DIM + swpos] = hv;
    } else {
        int r = row - BS;
        int swpos = (window << 5) + (((c ^ ((r >> 1) & 3)) << 3)) + off;
        float4 v = *(const float4*)&w[(size_t)r * DIM + h];
        ushort4 hv;
        hv.x = f2h(v.x); hv.y = f2h(v.y); hv.z = f2h(v.z); hv.w = f2h(v.w);
        *(ushort4*)&wf[(size_t)r * DIM + swpos] = hv;
        float s = v.x * v.x + v.y * v.y + v.z * v.z + v.w * v.w;
        #pragma unroll
        for (int o = 32; o; o >>= 1) s += __shfl_down(s, o, 64);
        if (lane == 0) wsq[r] = s;
    }
}

// ---------------------------------------------------------------------------
// BMU pass 1: fp16 GEMM, 128-sample tile x 8 sequential 128-k tiles (K=256).
// Per-k-tile fold into f32 running min; one shfl-reduce epilogue per block.
// keys[s] = atomicMin of fmap(approx min score).
__global__ __launch_bounds__(256) void bmu_pass1_kernel(
    const ushort* __restrict__ xf, const ushort* __restrict__ wf,
    const float* __restrict__ wsq, unsigned int* __restrict__ keys) {
    __shared__ ushort A[128 * 32];   //  8 KB
    __shared__ ushort B[128 * 32];   //  8 KB
    __shared__ float red[128][2];

    int m0 = blockIdx.x * 128;
    int kbase = blockIdx.y * 1024;
    int tid = threadIdx.x, w = tid >> 6, lane = tid & 63;
    int wm = (w & 1) * 64, wn = (w >> 1) * 64;
    int lm = lane & 15, quad = lane >> 4;
    int sw = (quad ^ ((lm >> 1) & 3)) * 8;   // conflict-free swizzled frag col
    int srow = lane >> 2, scol = (lane & 3) * 8;

    float best[4][4];
    #pragma unroll
    for (int mi = 0; mi < 4; ++mi)
        #pragma unroll
        for (int r = 0; r < 4; ++r) best[mi][r] = 3.4e38f;

    for (int kt = 0; kt < 8; ++kt) {
        int k0 = kbase + kt * 128;
        f32x4 acc[4][4];
        #pragma unroll
        for (int mi = 0; mi < 4; ++mi)
            #pragma unroll
            for (int ni = 0; ni < 4; ++ni)
                acc[mi][ni] = (f32x4){0.f, 0.f, 0.f, 0.f};

        for (int kb = 0; kb < DIM; kb += 32) {
            size_t axoff = (size_t)(m0 + w * 32 + srow) * DIM + kb + scol;
            size_t bxoff = (size_t)(k0 + w * 32 + srow) * DIM + kb + scol;
            gload_lds16(xf + axoff,            &A[(w * 32) * 32]);
            gload_lds16(xf + axoff + 16 * DIM, &A[(w * 32 + 16) * 32]);
            gload_lds16(wf + bxoff,            &B[(w * 32) * 32]);
            gload_lds16(wf + bxoff + 16 * DIM, &B[(w * 32 + 16) * 32]);
            __syncthreads();
            half8 av[4], bv[4];
            #pragma unroll
            for (int mi = 0; mi < 4; ++mi)
                av[mi] = *(const half8*)&A[(wm + mi * 16 + lm) * 32 + sw];
            #pragma unroll
            for (int ni = 0; ni < 4; ++ni)
                bv[ni] = *(const half8*)&B[(wn + ni * 16 + lm) * 32 + sw];
            #pragma unroll
            for (int mi = 0; mi < 4; ++mi)
                #pragma unroll
                for (int ni = 0; ni < 4; ++ni)
                    acc[mi][ni] = __builtin_amdgcn_mfma_f32_16x16x32_f16(
                        av[mi], bv[ni], acc[mi][ni], 0, 0, 0);
            __syncthreads();
        }
        // fold this k-tile into running min
        float wsqv[4];
        #pragma unroll
        for (int ni = 0; ni < 4; ++ni) wsqv[ni] = wsq[k0 + wn + ni * 16 + lm];
        #pragma unroll
        for (int mi = 0; mi < 4; ++mi)
            #pragma unroll
            for (int r = 0; r < 4; ++r) {
                #pragma unroll
                for (int ni = 0; ni < 4; ++ni) {
                    float sc = fmaf(-2.0f, acc[mi][ni][r], wsqv[ni]);
                    best[mi][r] = fminf(best[mi][r], sc);
                }
            }
    }
    // one epilogue: reduce across the 16 lm lanes, then 2 wave-pairs, atomicMin
    #pragma unroll
    for (int mi = 0; mi < 4; ++mi)
        #pragma unroll
        for (int r = 0; r < 4; ++r) {
            float b = best[mi][r];
            #pragma unroll
            for (int mask = 1; mask < 16; mask <<= 1)
                b = fminf(b, __shfl_xor(b, mask, 64));
            if (lm == 0) red[wm + mi * 16 + quad * 4 + r][w >> 1] = b;
        }
    __syncthreads();
    if (tid < 128) {
        float b = fminf(red[tid][0], red[tid][1]);
        atomicMin(&keys[m0 + tid], fmap(b));
    }
}

// ---------------------------------------------------------------------------
// BMU pass 2: identical GEMM (bit-identical scores); per-k-tile emit all k
// with score <= approxmin + MARGIN (hard-covers fp16 error) -> cand list.
__global__ __launch_bounds__(256) void bmu_pass2_kernel(
    const ushort* __restrict__ xf, const ushort* __restrict__ wf,
    const float* __restrict__ wsq, const unsigned int* __restrict__ keys,
    u64* __restrict__ cand, unsigned int* __restrict__ cnt) {
    __shared__ ushort A[128 * 32];
    __shared__ ushort B[128 * 32];

    int m0 = blockIdx.x * 128;
    int kbase = blockIdx.y * 1024;
    int tid = threadIdx.x, w = tid >> 6, lane = tid & 63;
    int wm = (w & 1) * 64, wn = (w >> 1) * 64;
    int lm = lane & 15, quad = lane >> 4;
    int sw = (quad ^ ((lm >> 1) & 3)) * 8;
    int srow = lane >> 2, scol = (lane & 3) * 8;

    float thr[4][4];
    #pragma unroll
    for (int mi = 0; mi < 4; ++mi)
        #pragma unroll
        for (int r = 0; r < 4; ++r)
            thr[mi][r] = unfmap(keys[m0 + wm + mi * 16 + quad * 4 + r]) + MARGIN;

    for (int kt = 0; kt < 8; ++kt) {
        int k0 = kbase + kt * 128;
        f32x4 acc[4][4];
        #pragma unroll
        for (int mi = 0; mi < 4; ++mi)
            #pragma unroll
            for (int ni = 0; ni < 4; ++ni)
                acc[mi][ni] = (f32x4){0.f, 0.f, 0.f, 0.f};

        for (int kb = 0; kb < DIM; kb += 32) {
            size_t axoff = (size_t)(m0 + w * 32 + srow) * DIM + kb + scol;
            size_t bxoff = (size_t)(k0 + w * 32 + srow) * DIM + kb + scol;
            gload_lds16(xf + axoff,            &A[(w * 32) * 32]);
            gload_lds16(xf + axoff + 16 * DIM, &A[(w * 32 + 16) * 32]);
            gload_lds16(wf + bxoff,            &B[(w * 32) * 32]);
            gload_lds16(wf + bxoff + 16 * DIM, &B[(w * 32 + 16) * 32]);
            __syncthreads();
            half8 av[4], bv[4];
            #pragma unroll
            for (int mi = 0; mi < 4; ++mi)
                av[mi] = *(const half8*)&A[(wm + mi * 16 + lm) * 32 + sw];
            #pragma unroll
            for (int ni = 0; ni < 4; ++ni)
                bv[ni] = *(const half8*)&B[(wn + ni * 16 + lm) * 32 + sw];
            #pragma unroll
            for (int mi = 0; mi < 4; ++mi)
                #pragma unroll
                for (int ni = 0; ni < 4; ++ni)
                    acc[mi][ni] = __builtin_amdgcn_mfma_f32_16x16x32_f16(
                        av[mi], bv[ni], acc[mi][ni], 0, 0, 0);
            __syncthreads();
        }
        // emit candidates for this k-tile
        float wsqv[4];
        #pragma unroll
        for (int ni = 0; ni < 4; ++ni) wsqv[ni] = wsq[k0 + wn + ni * 16 + lm];
        #pragma unroll
        for (int mi = 0; mi < 4; ++mi)
            #pragma unroll
            for (int r = 0; r < 4; ++r) {
                int s = m0 + wm + mi * 16 + quad * 4 + r;
                #pragma unroll
                for (int ni = 0; ni < 4; ++ni) {
                    float sc = fmaf(-2.0f, acc[mi][ni][r], wsqv[ni]);
                    if (sc <= thr[mi][r]) {
                        unsigned int idx = atomicAdd(cnt, 1u);
                        if (idx < CAND_CAP)
                            cand[idx] = ((u64)(unsigned int)s << 32) |
                                        (unsigned int)(k0 + wn + ni * 16 + lm);
                    }
                }
            }
    }
}

// ---------------------------------------------------------------------------
// BMU refine: exact f32 dist^2 per candidate, one wave per candidate.
__global__ __launch_bounds__(256) void bmu_refine_kernel(
    const float* __restrict__ x, const float* __restrict__ w,
    const u64* __restrict__ cand, const unsigned int* __restrict__ cnt,
    u64* __restrict__ keys2) {
    int lane = threadIdx.x & 63;
    int wid = blockIdx.x * 4 + (threadIdx.x >> 6);
    unsigned int n = cnt[0];
    if (n > CAND_CAP) n = CAND_CAP;
    for (unsigned int c = wid; c < n; c += 256 * 4) {
        u64 e = cand[c];
        unsigned int s = (unsigned int)(e >> 32);
        unsigned int k = (unsigned int)e;
        float4 xv = *(const float4*)&x[(size_t)s * DIM + lane * 4];
        float4 wv = *(const float4*)&w[(size_t)k * DIM + lane * 4];
        float dx = xv.x - wv.x, dy = xv.y - wv.y;
        float dz = xv.z - wv.z, dw = xv.w - wv.w;
        float d = dx * dx + dy * dy + dz * dz + dw * dw;
        #pragma unroll
        for (int off = 32; off; off >>= 1) d += __shfl_down(d, off, 64);
        if (lane == 0)
            atomicMin(&keys2[s], ((u64)fmap(d) << 32) | k);
    }
}

// ---------------------------------------------------------------------------
// scatter: S[bmu(s)][:] += x[s][:], cntf[bmu(s)] += 1.  One wave per sample.
__global__ __launch_bounds__(256) void scatter_kernel(
    const float* __restrict__ x, const u64* __restrict__ keys2,
    float* __restrict__ S, float* __restrict__ cntf) {
    int lane = threadIdx.x & 63;
    int s = blockIdx.x * 4 + (threadIdx.x >> 6);
    unsigned int k = (unsigned int)keys2[s];
    float4 xv = *(const float4*)&x[(size_t)s * DIM + lane * 4];
    float* Sp = &S[(size_t)k * DIM + lane * 4];
    atomicAdd(Sp + 0, xv.x);
    atomicAdd(Sp + 1, xv.y);
    atomicAdd(Sp + 2, xv.z);
    atomicAdd(Sp + 3, xv.w);
    if (lane == 0) atomicAdd(&cntf[k], 1.0f);
}

// ---------------------------------------------------------------------------
// gemm1: T[i][m] = sum_a G[i][a] * S[a][m], m in [0,32768), f32.
__global__ __launch_bounds__(256) void gemm1_kernel(
    const float* __restrict__ G, const float* __restrict__ S, float* __restrict__ T) {
    __shared__ float Sl[128 * 68];
    int n0 = blockIdx.x * 64;
    int tid = threadIdx.x;
    #pragma unroll
    for (int q = 0; q < 8; ++q) {
        int idx = q * 256 + tid;
        int row = idx >> 4, c4 = (idx & 15) * 4;
        *(float4*)&Sl[row * 68 + c4] = *(const float4*)&S[(size_t)row * 32768 + n0 + c4];
    }
    __syncthreads();
    int ng = tid & 15, ig = tid >> 4;
    for (int pass = 0; pass < 2; ++pass) {
        int ibase = pass * 64 + ig * 4;
        float acc[4][4] = {};
        for (int a = 0; a < 128; ++a) {
            float4 sv = *(const float4*)&Sl[a * 68 + ng * 4];
            #pragma unroll
            for (int ii = 0; ii < 4; ++ii) {
                float g = G[(ibase + ii) * 128 + a];
                acc[ii][0] = fmaf(g, sv.x, acc[ii][0]);
                acc[ii][1] = fmaf(g, sv.y, acc[ii][1]);
                acc[ii][2] = fmaf(g, sv.z, acc[ii][2]);
                acc[ii][3] = fmaf(g, sv.w, acc[ii][3]);
            }
        }
        #pragma unroll
        for (int ii = 0; ii < 4; ++ii)
            *(float4*)&T[(size_t)(ibase + ii) * 32768 + n0 + ng * 4] =
                *(float4*)&acc[ii][0];
    }
}

// ---------------------------------------------------------------------------
// denom stage 1: M1[a][j] = sum_b2 cntf[a][b2] * G[b2][j]
__global__ void denom_s1_kernel(const float* __restrict__ cntf, const float* __restrict__ G,
                                float* __restrict__ M1) {
    int a = blockIdx.x, j = threadIdx.x;
    float acc = 0.f;
    for (int b2 = 0; b2 < 128; ++b2)
        acc = fmaf(cntf[a * 128 + b2], G[b2 * 128 + j], acc);
    M1[a * 128 + j] = acc;
}

// denom stage 2: denom[i][j] = sum_a G[i][a] * M1[a][j]
__global__ void denom_s2_kernel(const float* __restrict__ G, const float* __restrict__ M1,
                                float* __restrict__ denom) {
    int i = blockIdx.x, j = threadIdx.x;
    float acc = 0.f;
    for (int a = 0; a < 128; ++a)
        acc = fmaf(G[i * 128 + a], M1[a * 128 + j], acc);
    denom[i * 128 + j] = acc;
}

// ---------------------------------------------------------------------------
// gemm2 + finalize: out[i][j][d] = (sum_b2 G[j][b2] T[i][b2*256+d]) / denom[i][j]
__global__ __launch_bounds__(256) void gemm2_fin_kernel(
    const float* __restrict__ G, const float* __restrict__ T,
    const float* __restrict__ denom, const float* __restrict__ w,
    float* __restrict__ out) {
    __shared__ float Tl[128 * 68];
    int i = blockIdx.x, dq = blockIdx.y;
    int tid = threadIdx.x;
    #pragma unroll
    for (int q = 0; q < 8; ++q) {
        int idx = q * 256 + tid;
        int row = idx >> 4, c4 = (idx & 15) * 4;
        *(float4*)&Tl[row * 68 + c4] =
            *(const float4*)&T[(size_t)i * 32768 + row * 256 + dq * 64 + c4];
    }
    __syncthreads();
    int dg = tid & 15, jg = tid >> 4;
    for (int pass = 0; pass < 2; ++pass) {
        int jbase = pass * 64 + jg * 4;
        float acc[4][4] = {};
        for (int b2 = 0; b2 < 128; ++b2) {
            float4 tv = *(const float4*)&Tl[b2 * 68 + dg * 4];
            #pragma unroll
            for (int jj = 0; jj < 4; ++jj) {
                float g = G[(jbase + jj) * 128 + b2];
                acc[jj][0] = fmaf(g, tv.x, acc[jj][0]);
                acc[jj][1] = fmaf(g, tv.y, acc[jj][1]);
                acc[jj][2] = fmaf(g, tv.z, acc[jj][2]);
                acc[jj][3] = fmaf(g, tv.w, acc[jj][3]);
            }
        }
        #pragma unroll
        for (int jj = 0; jj < 4; ++jj) {
            int j = jbase + jj;
            float dv = denom[i * 128 + j];
            size_t e = (size_t)(i * 128 + j) * DIM + dq * 64 + dg * 4;
            float4 r;
            if (dv != 0.0f) {
                float inv = 1.0f / dv;
                r.x = acc[jj][0] * inv; r.y = acc[jj][1] * inv;
                r.z = acc[jj][2] * inv; r.w = acc[jj][3] * inv;
            } else {
                r = *(const float4*)&w[e];
            }
            *(float4*)&out[e] = r;
        }
    }
}

// ---------------------------------------------------------------------------
extern "C" void kernel_launch(void* const* d_in, const int* in_sizes, int n_in,
                              void* d_out, int out_size, void* d_ws, size_t ws_size,
                              hipStream_t stream) {
    const float* data = (const float*)d_in[0];   // [8192, 256] f32
    const float* w    = (const float*)d_in[1];   // [128,128,256] f32
    const int*   itp  = (const int*)d_in[2];     // scalar
    float* out = (float*)d_out;                  // [128,128,256] f32

    char* ws = (char*)d_ws;
    size_t off = 0;
    float*        wsq   = (float*)(ws + off);        off += 65536;     //  64 KB
    unsigned int* keys  = (unsigned int*)(ws + off); off += 65536;     //  64 KB (u32 fmap scores)
    u64*          keys2 = (u64*)(ws + off);          off += 65536;     //  64 KB (exact dist|k)
    unsigned int* cnt   = (unsigned int*)(ws + off); off += 65536;     //  64 KB
    float*        G     = (float*)(ws + off);        off += 65536;     //  64 KB [128][128]
    float*        cntf  = (float*)(ws + off);        off += 65536;     //  64 KB [a][b2]
    float*        M1    = (float*)(ws + off);        off += 65536;     //  64 KB
    float*        denom = (float*)(ws + off);        off += 65536;     //  64 KB
    ushort*       xf    = (ushort*)(ws + off);       off += 4194304;   //   4 MB fp16 swizzled
    ushort*       wf    = (ushort*)(ws + off);       off += 8388608;   //   8 MB fp16 swizzled
    u64*          cand  = (u64*)(ws + off);          off += 1048576;   //   1 MB
    float*        S     = (float*)(ws + off);        off += 16777216;  //  16 MB [c][d]
    float*        T     = (float*)(ws + off);        off += 16777216;  //  16 MB [i][32768]

    setup_all_kernel<<<4096, 256, 0, stream>>>(S, G, cntf, keys, keys2, cnt, itp);
    cvt_all_kernel<<<(BS + KTOT) / 4, 256, 0, stream>>>(data, w, xf, wf, wsq);
    bmu_pass1_kernel<<<dim3(64, 16), 256, 0, stream>>>(xf, wf, wsq, keys);
    bmu_pass2_kernel<<<dim3(64, 16), 256, 0, stream>>>(xf, wf, wsq, keys, cand, cnt);
    bmu_refine_kernel<<<256, 256, 0, stream>>>(data, w, cand, cnt, keys2);
    scatter_kernel<<<BS / 4, 256, 0, stream>>>(data, keys2, S, cntf);
    gemm1_kernel<<<512, 256, 0, stream>>>(G, S, T);
    denom_s1_kernel<<<128, 128, 0, stream>>>(cntf, G, M1);
    denom_s2_kernel<<<128, 128, 0, stream>>>(G, M1, denom);
    gemm2_fin_kernel<<<dim3(128, 4), 256, 0, stream>>>(G, T, denom, w, out);
}